// Round 4
// baseline (7280.151 us; speedup 1.0000x reference)
//
#include <hip/hip_runtime.h>
#include <hip/hip_bf16.h>

#define N_USERS 100000
#define N_NODES 150000
#define EMB 64
#define RPB 128              // rows per bucket
#define SH 7                 // log2(RPB)
#define NB 1172              // ceil(150000/128)
#define CHUNK 16384

typedef __hip_bfloat16 bf16;

static __device__ inline float bf2f(unsigned short u) {
    return __uint_as_float((unsigned)u << 16);
}
static __device__ inline unsigned short f2bf(float f) {
    bf16 h = __float2bfloat16(f);
    return *reinterpret_cast<unsigned short*>(&h);
}

// ---- bucket histogram: LDS-combined then global flush ----
__global__ __launch_bounds__(256)
void bucket_hist(const int* __restrict__ rows, int* __restrict__ bh, int nedges) {
    __shared__ int lh[NB];
    int tid = threadIdx.x;
    for (int i = tid; i < NB; i += 256) lh[i] = 0;
    __syncthreads();
    int stride = gridDim.x * blockDim.x;
    for (int e = blockIdx.x * blockDim.x + tid; e < nedges; e += stride)
        atomicAdd(&lh[rows[e] >> SH], 1);
    __syncthreads();
    for (int b = tid; b < NB; b += 256) {
        int h = lh[b];
        if (h) atomicAdd(&bh[b], h);
    }
}

// ---- single-block exclusive scan of NB bucket counts ----
__global__ __launch_bounds__(1024)
void scan_single(const int* __restrict__ bh, int* __restrict__ base,
                 int* __restrict__ cursor, int nedges) {
    __shared__ int wsum[16];
    __shared__ int carry;
    int tid = threadIdx.x, lane = tid & 63, wid = tid >> 6;
    if (tid == 0) carry = 0;
    __syncthreads();
    for (int t0 = 0; t0 < NB; t0 += 1024) {
        int i = t0 + tid;
        int v = (i < NB) ? bh[i] : 0;
        int s = v;
        #pragma unroll
        for (int d = 1; d < 64; d <<= 1) { int t = __shfl_up(s, d); if (lane >= d) s += t; }
        if (lane == 63) wsum[wid] = s;
        __syncthreads();
        if (wid == 0 && lane < 16) {
            int w = wsum[lane];
            #pragma unroll
            for (int d = 1; d < 16; d <<= 1) { int t = __shfl_up(w, d); if (lane >= d) w += t; }
            wsum[lane] = w;
        }
        __syncthreads();
        int excl = (wid ? wsum[wid - 1] : 0) + (s - v) + carry;
        if (i < NB) { base[i] = excl; cursor[i] = excl; }
        __syncthreads();
        if (tid == 1023) carry += wsum[15];
        __syncthreads();
    }
    if (tid == 0) base[NB] = nedges;
}

// ---- chunked scatter into bucket-grouped records (coalesced runs) ----
__global__ __launch_bounds__(512)
void bucket_scatter(const int* __restrict__ rows, const int* __restrict__ cols,
                    const float* __restrict__ vals, int* __restrict__ cursor,
                    int2* __restrict__ rec, int nedges) {
    __shared__ int lh[NB], gb[NB], lc[NB];
    int tid = threadIdx.x;
    int cs = blockIdx.x * CHUNK;
    int cn = min(CHUNK, nedges - cs);
    for (int i = tid; i < NB; i += 512) { lh[i] = 0; lc[i] = 0; }
    __syncthreads();
    for (int i = tid; i < cn; i += 512)
        atomicAdd(&lh[rows[cs + i] >> SH], 1);
    __syncthreads();
    for (int b = tid; b < NB; b += 512) {
        int h = lh[b];
        if (h) gb[b] = atomicAdd(&cursor[b], h);
    }
    __syncthreads();
    for (int i = tid; i < cn; i += 512) {
        int e = cs + i;
        int r = rows[e];
        int b = r >> SH;
        int p = atomicAdd(&lc[b], 1);
        rec[gb[b] + p] = make_int2(((r & (RPB - 1)) << 18) | cols[e],
                                   __float_as_int(vals[e]));
    }
}

// ---- convert f32 (ue|ie) -> contiguous bf16 ego table ----
__global__ __launch_bounds__(256)
void cvt_ego(const float* __restrict__ ue, const float* __restrict__ ie,
             unsigned short* __restrict__ ego) {
    const int total4 = N_NODES * EMB / 4;
    const int userEnd4 = N_USERS * EMB / 4;
    int stride = gridDim.x * blockDim.x;
    for (int i = blockIdx.x * blockDim.x + threadIdx.x; i < total4; i += stride) {
        float4 v = (i < userEnd4) ? ((const float4*)ue)[i]
                                  : ((const float4*)ie)[i - userEnd4];
        ushort4 o;
        o.x = f2bf(v.x); o.y = f2bf(v.y); o.z = f2bf(v.z); o.w = f2bf(v.w);
        ((ushort4*)ego)[i] = o;
    }
}

// ---- SpMM: one block per bucket; coalesced edge loads + shfl broadcast,
//      8-wide independent gathers, LDS f32 accumulator ----
__global__ __launch_bounds__(512)
void spmm_bucket(const int2* __restrict__ rec, const int* __restrict__ base,
                 const unsigned short* __restrict__ x, unsigned short* __restrict__ y) {
    __shared__ float acc[RPB * EMB];   // 32 KB
    const int b = blockIdx.x;
    const int tid = threadIdx.x, lane = tid & 63, wave = tid >> 6;
    for (int i = tid; i < RPB * EMB; i += 512) acc[i] = 0.f;
    __syncthreads();
    const int s = base[b], e = base[b + 1];
    for (int k0 = s + wave * 64; k0 < e; k0 += 512) {
        int kk = k0 + lane;
        int2 r = make_int2(0, 0);
        if (kk < e) r = rec[kk];          // coalesced: 64 edges per wave
        int cnt = min(64, e - k0);
        int j = 0;
        for (; j + 8 <= cnt; j += 8) {
            unsigned p0 = (unsigned)__shfl(r.x, j + 0); float v0 = __int_as_float(__shfl(r.y, j + 0));
            unsigned p1 = (unsigned)__shfl(r.x, j + 1); float v1 = __int_as_float(__shfl(r.y, j + 1));
            unsigned p2 = (unsigned)__shfl(r.x, j + 2); float v2 = __int_as_float(__shfl(r.y, j + 2));
            unsigned p3 = (unsigned)__shfl(r.x, j + 3); float v3 = __int_as_float(__shfl(r.y, j + 3));
            unsigned p4 = (unsigned)__shfl(r.x, j + 4); float v4 = __int_as_float(__shfl(r.y, j + 4));
            unsigned p5 = (unsigned)__shfl(r.x, j + 5); float v5 = __int_as_float(__shfl(r.y, j + 5));
            unsigned p6 = (unsigned)__shfl(r.x, j + 6); float v6 = __int_as_float(__shfl(r.y, j + 6));
            unsigned p7 = (unsigned)__shfl(r.x, j + 7); float v7 = __int_as_float(__shfl(r.y, j + 7));
            float x0 = bf2f(x[(size_t)(p0 & 0x3FFFF) * EMB + lane]);
            float x1 = bf2f(x[(size_t)(p1 & 0x3FFFF) * EMB + lane]);
            float x2 = bf2f(x[(size_t)(p2 & 0x3FFFF) * EMB + lane]);
            float x3 = bf2f(x[(size_t)(p3 & 0x3FFFF) * EMB + lane]);
            float x4 = bf2f(x[(size_t)(p4 & 0x3FFFF) * EMB + lane]);
            float x5 = bf2f(x[(size_t)(p5 & 0x3FFFF) * EMB + lane]);
            float x6 = bf2f(x[(size_t)(p6 & 0x3FFFF) * EMB + lane]);
            float x7 = bf2f(x[(size_t)(p7 & 0x3FFFF) * EMB + lane]);
            atomicAdd(&acc[(p0 >> 18) * EMB + lane], v0 * x0);
            atomicAdd(&acc[(p1 >> 18) * EMB + lane], v1 * x1);
            atomicAdd(&acc[(p2 >> 18) * EMB + lane], v2 * x2);
            atomicAdd(&acc[(p3 >> 18) * EMB + lane], v3 * x3);
            atomicAdd(&acc[(p4 >> 18) * EMB + lane], v4 * x4);
            atomicAdd(&acc[(p5 >> 18) * EMB + lane], v5 * x5);
            atomicAdd(&acc[(p6 >> 18) * EMB + lane], v6 * x6);
            atomicAdd(&acc[(p7 >> 18) * EMB + lane], v7 * x7);
        }
        for (; j < cnt; ++j) {
            unsigned pj = (unsigned)__shfl(r.x, j); float vj = __int_as_float(__shfl(r.y, j));
            float xj = bf2f(x[(size_t)(pj & 0x3FFFF) * EMB + lane]);
            atomicAdd(&acc[(pj >> 18) * EMB + lane], vj * xj);
        }
    }
    __syncthreads();
    int rowbase = b * RPB;
    int nrows = min(RPB, N_NODES - rowbase);
    for (int jr = wave; jr < nrows; jr += 8)
        y[(size_t)(rowbase + jr) * EMB + lane] = f2bf(acc[jr * EMB + lane]);
}

// ---- batch-row output kernels ----
__global__ void out_init(const int* __restrict__ user, const int* __restrict__ item,
                         const float* __restrict__ ue, const float* __restrict__ ie,
                         float* __restrict__ out, int batch) {
    int wave = (blockIdx.x * blockDim.x + threadIdx.x) >> 6;
    int lane = threadIdx.x & 63;
    if (wave < batch)
        out[(size_t)wave * EMB + lane] = ue[(size_t)user[wave] * EMB + lane];
    else if (wave < 2 * batch)
        out[(size_t)wave * EMB + lane] = ie[(size_t)item[wave - batch] * EMB + lane];
}

__global__ void out_add(const int* __restrict__ user, const int* __restrict__ item,
                        const unsigned short* __restrict__ h, float* __restrict__ out,
                        int batch, float scale) {
    int wave = (blockIdx.x * blockDim.x + threadIdx.x) >> 6;
    int lane = threadIdx.x & 63;
    if (wave < 2 * batch) {
        int node = (wave < batch) ? user[wave] : (N_USERS + item[wave - batch]);
        size_t o = (size_t)wave * EMB + lane;
        out[o] = (out[o] + bf2f(h[(size_t)node * EMB + lane])) * scale;
    }
}

// ---- driver ----
extern "C" void kernel_launch(void* const* d_in, const int* in_sizes, int n_in,
                              void* d_out, int out_size, void* d_ws, size_t ws_size,
                              hipStream_t stream) {
    const int*   user = (const int*)d_in[0];
    const int*   item = (const int*)d_in[1];
    const int*   rows = (const int*)d_in[2];
    const int*   cols = (const int*)d_in[3];
    const float* vals = (const float*)d_in[4];
    const float* ue   = (const float*)d_in[5];
    const float* ie   = (const float*)d_in[6];
    float*       out  = (float*)d_out;

    const int nedges = in_sizes[2];
    const int batch  = in_sizes[0];

    const size_t hElems = (size_t)N_NODES * EMB;
    char* p = (char*)d_ws;
    int2*           rec    = (int2*)p;            p += (size_t)nedges * sizeof(int2); // 51.2 MB
    int*            bh     = (int*)p;             p += 8192;
    int*            base   = (int*)p;             p += 8192;   // NB+1 ints
    int*            cursor = (int*)p;             p += 8192;
    unsigned short* ego    = (unsigned short*)p;  p += hElems * 2;   // 19.2 MB
    unsigned short* hA     = (unsigned short*)p;  p += hElems * 2;
    unsigned short* hB     = (unsigned short*)p;  p += hElems * 2;

    // --- bucket sort (coarse) ---
    hipMemsetAsync(bh, 0, NB * sizeof(int), stream);
    bucket_hist<<<1024, 256, 0, stream>>>(rows, bh, nedges);
    scan_single<<<1, 1024, 0, stream>>>(bh, base, cursor, nedges);
    bucket_scatter<<<(nedges + CHUNK - 1) / CHUNK, 512, 0, stream>>>(
        rows, cols, vals, cursor, rec, nedges);

    // --- ego table in bf16 ---
    cvt_ego<<<2048, 256, 0, stream>>>(ue, ie, ego);

    // --- out = ego[sel] (f32, exact) ---
    const int oblocks = (2 * batch * 64) / 256;
    out_init<<<oblocks, 256, 0, stream>>>(user, item, ue, ie, out, batch);

    // --- 3 propagation layers ---
    spmm_bucket<<<NB, 512, 0, stream>>>(rec, base, ego, hA);
    out_add<<<oblocks, 256, 0, stream>>>(user, item, hA, out, batch, 1.0f);

    spmm_bucket<<<NB, 512, 0, stream>>>(rec, base, hA, hB);
    out_add<<<oblocks, 256, 0, stream>>>(user, item, hB, out, batch, 1.0f);

    spmm_bucket<<<NB, 512, 0, stream>>>(rec, base, hB, hA);
    out_add<<<oblocks, 256, 0, stream>>>(user, item, hA, out, batch, 0.25f);
}

// Round 5
// 717.005 us; speedup vs baseline: 10.1536x; 10.1536x over previous
//
#include <hip/hip_runtime.h>
#include <hip/hip_bf16.h>

#define N_USERS 100000
#define N_NODES 150000
#define EMB 64
#define RPB 128              // rows per bucket
#define SH 7                 // log2(RPB)
#define NB 1172              // ceil(150000/128)
#define CHUNK 16384
#define CAP 8192             // per-bucket LDS record capacity (mean 5461, 37 sigma)

typedef __hip_bfloat16 bf16;

static __device__ inline float bf2f(unsigned short u) {
    return __uint_as_float((unsigned)u << 16);
}
static __device__ inline unsigned short f2bf(float f) {
    bf16 h = __float2bfloat16(f);
    return *reinterpret_cast<unsigned short*>(&h);
}

// ---- bucket histogram: LDS-combined then global flush ----
__global__ __launch_bounds__(256)
void bucket_hist(const int* __restrict__ rows, int* __restrict__ bh, int nedges) {
    __shared__ int lh[NB];
    int tid = threadIdx.x;
    for (int i = tid; i < NB; i += 256) lh[i] = 0;
    __syncthreads();
    int stride = gridDim.x * blockDim.x;
    for (int e = blockIdx.x * blockDim.x + tid; e < nedges; e += stride)
        atomicAdd(&lh[rows[e] >> SH], 1);
    __syncthreads();
    for (int b = tid; b < NB; b += 256) {
        int h = lh[b];
        if (h) atomicAdd(&bh[b], h);
    }
}

// ---- single-block exclusive scan of NB bucket counts ----
__global__ __launch_bounds__(1024)
void scan_single(const int* __restrict__ bh, int* __restrict__ base,
                 int* __restrict__ cursor, int nedges) {
    __shared__ int wsum[16];
    __shared__ int carry;
    int tid = threadIdx.x, lane = tid & 63, wid = tid >> 6;
    if (tid == 0) carry = 0;
    __syncthreads();
    for (int t0 = 0; t0 < NB; t0 += 1024) {
        int i = t0 + tid;
        int v = (i < NB) ? bh[i] : 0;
        int s = v;
        #pragma unroll
        for (int d = 1; d < 64; d <<= 1) { int t = __shfl_up(s, d); if (lane >= d) s += t; }
        if (lane == 63) wsum[wid] = s;
        __syncthreads();
        if (wid == 0 && lane < 16) {
            int w = wsum[lane];
            #pragma unroll
            for (int d = 1; d < 16; d <<= 1) { int t = __shfl_up(w, d); if (lane >= d) w += t; }
            wsum[lane] = w;
        }
        __syncthreads();
        int excl = (wid ? wsum[wid - 1] : 0) + (s - v) + carry;
        if (i < NB) { base[i] = excl; cursor[i] = excl; }
        __syncthreads();
        if (tid == 1023) carry += wsum[15];
        __syncthreads();
    }
    if (tid == 0) base[NB] = nedges;
}

// ---- chunked scatter into bucket-grouped records (coalesced runs) ----
// rec entry: x = (row_local << 18) | col, y = bits(val)
__global__ __launch_bounds__(512)
void bucket_scatter(const int* __restrict__ rows, const int* __restrict__ cols,
                    const float* __restrict__ vals, int* __restrict__ cursor,
                    int2* __restrict__ rec, int nedges) {
    __shared__ int lh[NB], gb[NB], lc[NB];
    int tid = threadIdx.x;
    int cs = blockIdx.x * CHUNK;
    int cn = min(CHUNK, nedges - cs);
    for (int i = tid; i < NB; i += 512) { lh[i] = 0; lc[i] = 0; }
    __syncthreads();
    for (int i = tid; i < cn; i += 512)
        atomicAdd(&lh[rows[cs + i] >> SH], 1);
    __syncthreads();
    for (int b = tid; b < NB; b += 512) {
        int h = lh[b];
        if (h) gb[b] = atomicAdd(&cursor[b], h);
    }
    __syncthreads();
    for (int i = tid; i < cn; i += 512) {
        int e = cs + i;
        int r = rows[e];
        int b = r >> SH;
        int p = atomicAdd(&lc[b], 1);
        rec[gb[b] + p] = make_int2(((r & (RPB - 1)) << 18) | cols[e],
                                   __float_as_int(vals[e]));
    }
}

// ---- per-bucket LDS counting sort: rec (bucket-grouped) -> rec (row-sorted,
//      repacked as (col,val)), and emit full CSR row_start ----
__global__ __launch_bounds__(512)
void sort_bucket(int2* __restrict__ rec, const int* __restrict__ base,
                 int* __restrict__ row_start) {
    __shared__ int2 lrec[CAP];                 // 64 KB
    __shared__ int cnt[RPB], cur[RPB];
    __shared__ int wtot;
    const int b = blockIdx.x, tid = threadIdx.x;
    const int s = base[b], e = base[b + 1], n = e - s;
    for (int i = tid; i < RPB; i += 512) cnt[i] = 0;
    __syncthreads();
    for (int i = tid; i < n; i += 512) {
        int2 r = rec[s + i];                   // coalesced
        lrec[i] = r;
        atomicAdd(&cnt[((unsigned)r.x) >> 18], 1);
    }
    __syncthreads();
    // exclusive scan of cnt[0..127] using waves 0,1
    int lane = tid & 63;
    int v = (tid < 128) ? cnt[tid] : 0;
    int sc = v;
    #pragma unroll
    for (int d = 1; d < 64; d <<= 1) { int t = __shfl_up(sc, d); if (lane >= d) sc += t; }
    if (tid == 63) wtot = sc;
    __syncthreads();
    if (tid < 128) {
        int ex = sc - v + ((tid >= 64) ? wtot : 0);
        cur[tid] = ex;
        int idx = b * RPB + tid;
        if (idx <= N_NODES) row_start[idx] = s + ex;
    }
    __syncthreads();
    for (int i = tid; i < n; i += 512) {
        int2 r = lrec[i];
        unsigned rx = (unsigned)r.x;
        int pos = atomicAdd(&cur[rx >> 18], 1);
        rec[s + pos] = make_int2((int)(rx & 0x3FFFF), r.y);   // (col, val)
    }
}

// ---- convert f32 (ue|ie) -> contiguous bf16 ego table ----
__global__ __launch_bounds__(256)
void cvt_ego(const float* __restrict__ ue, const float* __restrict__ ie,
             unsigned short* __restrict__ ego) {
    const int total4 = N_NODES * EMB / 4;
    const int userEnd4 = N_USERS * EMB / 4;
    int stride = gridDim.x * blockDim.x;
    for (int i = blockIdx.x * blockDim.x + threadIdx.x; i < total4; i += stride) {
        float4 v = (i < userEnd4) ? ((const float4*)ue)[i]
                                  : ((const float4*)ie)[i - userEnd4];
        ushort4 o;
        o.x = f2bf(v.x); o.y = f2bf(v.y); o.z = f2bf(v.z); o.w = f2bf(v.w);
        ((ushort4*)ego)[i] = o;
    }
}

// ---- SpMM: one wave per row, register accumulate, 8-wide unrolled gathers ----
__global__ __launch_bounds__(256)
void spmm_row(const int2* __restrict__ rec, const int* __restrict__ row_start,
              const unsigned short* __restrict__ x, unsigned short* __restrict__ y) {
    const int lane = threadIdx.x & 63;
    const int wave = (blockIdx.x * blockDim.x + threadIdx.x) >> 6;
    const int nw = (gridDim.x * blockDim.x) >> 6;
    for (int r = wave; r < N_NODES; r += nw) {
        const int s = row_start[r], e = row_start[r + 1];
        float acc = 0.f;
        for (int k0 = s; k0 < e; k0 += 64) {
            int kk = k0 + lane;
            int2 rc = make_int2(0, 0);
            if (kk < e) rc = rec[kk];          // coalesced: 64 edges per wave
            int cnt = min(64, e - k0);
            int j = 0;
            for (; j + 8 <= cnt; j += 8) {
                int c0 = __shfl(rc.x, j + 0); float v0 = __int_as_float(__shfl(rc.y, j + 0));
                int c1 = __shfl(rc.x, j + 1); float v1 = __int_as_float(__shfl(rc.y, j + 1));
                int c2 = __shfl(rc.x, j + 2); float v2 = __int_as_float(__shfl(rc.y, j + 2));
                int c3 = __shfl(rc.x, j + 3); float v3 = __int_as_float(__shfl(rc.y, j + 3));
                int c4 = __shfl(rc.x, j + 4); float v4 = __int_as_float(__shfl(rc.y, j + 4));
                int c5 = __shfl(rc.x, j + 5); float v5 = __int_as_float(__shfl(rc.y, j + 5));
                int c6 = __shfl(rc.x, j + 6); float v6 = __int_as_float(__shfl(rc.y, j + 6));
                int c7 = __shfl(rc.x, j + 7); float v7 = __int_as_float(__shfl(rc.y, j + 7));
                float x0 = bf2f(x[(size_t)c0 * EMB + lane]);
                float x1 = bf2f(x[(size_t)c1 * EMB + lane]);
                float x2 = bf2f(x[(size_t)c2 * EMB + lane]);
                float x3 = bf2f(x[(size_t)c3 * EMB + lane]);
                float x4 = bf2f(x[(size_t)c4 * EMB + lane]);
                float x5 = bf2f(x[(size_t)c5 * EMB + lane]);
                float x6 = bf2f(x[(size_t)c6 * EMB + lane]);
                float x7 = bf2f(x[(size_t)c7 * EMB + lane]);
                acc = fmaf(v0, x0, acc);
                acc = fmaf(v1, x1, acc);
                acc = fmaf(v2, x2, acc);
                acc = fmaf(v3, x3, acc);
                acc = fmaf(v4, x4, acc);
                acc = fmaf(v5, x5, acc);
                acc = fmaf(v6, x6, acc);
                acc = fmaf(v7, x7, acc);
            }
            for (; j < cnt; ++j) {
                int cj = __shfl(rc.x, j); float vj = __int_as_float(__shfl(rc.y, j));
                acc = fmaf(vj, bf2f(x[(size_t)cj * EMB + lane]), acc);
            }
        }
        y[(size_t)r * EMB + lane] = f2bf(acc);
    }
}

// ---- batch-row output kernels ----
__global__ void out_init(const int* __restrict__ user, const int* __restrict__ item,
                         const float* __restrict__ ue, const float* __restrict__ ie,
                         float* __restrict__ out, int batch) {
    int wave = (blockIdx.x * blockDim.x + threadIdx.x) >> 6;
    int lane = threadIdx.x & 63;
    if (wave < batch)
        out[(size_t)wave * EMB + lane] = ue[(size_t)user[wave] * EMB + lane];
    else if (wave < 2 * batch)
        out[(size_t)wave * EMB + lane] = ie[(size_t)item[wave - batch] * EMB + lane];
}

__global__ void out_add(const int* __restrict__ user, const int* __restrict__ item,
                        const unsigned short* __restrict__ h, float* __restrict__ out,
                        int batch, float scale) {
    int wave = (blockIdx.x * blockDim.x + threadIdx.x) >> 6;
    int lane = threadIdx.x & 63;
    if (wave < 2 * batch) {
        int node = (wave < batch) ? user[wave] : (N_USERS + item[wave - batch]);
        size_t o = (size_t)wave * EMB + lane;
        out[o] = (out[o] + bf2f(h[(size_t)node * EMB + lane])) * scale;
    }
}

// ---- driver ----
extern "C" void kernel_launch(void* const* d_in, const int* in_sizes, int n_in,
                              void* d_out, int out_size, void* d_ws, size_t ws_size,
                              hipStream_t stream) {
    const int*   user = (const int*)d_in[0];
    const int*   item = (const int*)d_in[1];
    const int*   rows = (const int*)d_in[2];
    const int*   cols = (const int*)d_in[3];
    const float* vals = (const float*)d_in[4];
    const float* ue   = (const float*)d_in[5];
    const float* ie   = (const float*)d_in[6];
    float*       out  = (float*)d_out;

    const int nedges = in_sizes[2];
    const int batch  = in_sizes[0];

    const size_t hElems = (size_t)N_NODES * EMB;
    char* p = (char*)d_ws;
    int2*           rec       = (int2*)p;            p += (size_t)nedges * sizeof(int2); // 51.2 MB
    int*            bh        = (int*)p;             p += 8192;
    int*            base      = (int*)p;             p += 8192;   // NB+1 ints
    int*            cursor    = (int*)p;             p += 8192;
    int*            row_start = (int*)p;             p += 600064; // N_NODES+1 ints, padded
    unsigned short* ego       = (unsigned short*)p;  p += hElems * 2;   // 19.2 MB
    unsigned short* hA        = (unsigned short*)p;  p += hElems * 2;
    unsigned short* hB        = (unsigned short*)p;  p += hElems * 2;

    // --- CSR build: coarse bucket sort, then per-bucket LDS counting sort ---
    hipMemsetAsync(bh, 0, NB * sizeof(int), stream);
    bucket_hist<<<1024, 256, 0, stream>>>(rows, bh, nedges);
    scan_single<<<1, 1024, 0, stream>>>(bh, base, cursor, nedges);
    bucket_scatter<<<(nedges + CHUNK - 1) / CHUNK, 512, 0, stream>>>(
        rows, cols, vals, cursor, rec, nedges);
    sort_bucket<<<NB, 512, 0, stream>>>(rec, base, row_start);

    // --- ego table in bf16 ---
    cvt_ego<<<2048, 256, 0, stream>>>(ue, ie, ego);

    // --- out = ego[sel] (f32, exact) ---
    const int oblocks = (2 * batch * 64) / 256;
    out_init<<<oblocks, 256, 0, stream>>>(user, item, ue, ie, out, batch);

    // --- 3 propagation layers (wave-per-row, register acc) ---
    spmm_row<<<2048, 256, 0, stream>>>(rec, row_start, ego, hA);
    out_add<<<oblocks, 256, 0, stream>>>(user, item, hA, out, batch, 1.0f);

    spmm_row<<<2048, 256, 0, stream>>>(rec, row_start, hA, hB);
    out_add<<<oblocks, 256, 0, stream>>>(user, item, hB, out, batch, 1.0f);

    spmm_row<<<2048, 256, 0, stream>>>(rec, row_start, hB, hA);
    out_add<<<oblocks, 256, 0, stream>>>(user, item, hA, out, batch, 0.25f);
}

// Round 6
// 698.299 us; speedup vs baseline: 10.4256x; 1.0268x over previous
//
#include <hip/hip_runtime.h>
#include <hip/hip_bf16.h>

#define N_USERS 100000
#define N_NODES 150000
#define EMB 64
#define RPB 128              // rows per bucket
#define SH 7                 // log2(RPB)
#define NB 1172              // ceil(150000/128)
#define CHUNK 32768
#define CAP 8192             // per-bucket LDS record capacity (mean 5461, 37 sigma)

typedef __hip_bfloat16 bf16;

static __device__ inline float bf2f(unsigned short u) {
    return __uint_as_float((unsigned)u << 16);
}
static __device__ inline unsigned short f2bf(float f) {
    bf16 h = __float2bfloat16(f);
    return *reinterpret_cast<unsigned short*>(&h);
}

// ---- bucket histogram: LDS-combined then global flush ----
__global__ __launch_bounds__(256)
void bucket_hist(const int* __restrict__ rows, int* __restrict__ bh, int nedges) {
    __shared__ int lh[NB];
    int tid = threadIdx.x;
    for (int i = tid; i < NB; i += 256) lh[i] = 0;
    __syncthreads();
    int stride = gridDim.x * blockDim.x;
    for (int e = blockIdx.x * blockDim.x + tid; e < nedges; e += stride)
        atomicAdd(&lh[rows[e] >> SH], 1);
    __syncthreads();
    for (int b = tid; b < NB; b += 256) {
        int h = lh[b];
        if (h) atomicAdd(&bh[b], h);
    }
}

// ---- single-block exclusive scan of NB bucket counts ----
__global__ __launch_bounds__(1024)
void scan_single(const int* __restrict__ bh, int* __restrict__ base,
                 int* __restrict__ cursor, int nedges) {
    __shared__ int wsum[16];
    __shared__ int carry;
    int tid = threadIdx.x, lane = tid & 63, wid = tid >> 6;
    if (tid == 0) carry = 0;
    __syncthreads();
    for (int t0 = 0; t0 < NB; t0 += 1024) {
        int i = t0 + tid;
        int v = (i < NB) ? bh[i] : 0;
        int s = v;
        #pragma unroll
        for (int d = 1; d < 64; d <<= 1) { int t = __shfl_up(s, d); if (lane >= d) s += t; }
        if (lane == 63) wsum[wid] = s;
        __syncthreads();
        if (wid == 0 && lane < 16) {
            int w = wsum[lane];
            #pragma unroll
            for (int d = 1; d < 16; d <<= 1) { int t = __shfl_up(w, d); if (lane >= d) w += t; }
            wsum[lane] = w;
        }
        __syncthreads();
        int excl = (wid ? wsum[wid - 1] : 0) + (s - v) + carry;
        if (i < NB) { base[i] = excl; cursor[i] = excl; }
        __syncthreads();
        if (tid == 1023) carry += wsum[15];
        __syncthreads();
    }
    if (tid == 0) base[NB] = nedges;
}

// ---- chunked scatter into bucket-grouped records (coalesced runs) ----
// rec entry: x = (row_local << 18) | col, y = bits(val)
__global__ __launch_bounds__(512)
void bucket_scatter(const int* __restrict__ rows, const int* __restrict__ cols,
                    const float* __restrict__ vals, int* __restrict__ cursor,
                    int2* __restrict__ rec, int nedges) {
    __shared__ int lh[NB], gb[NB], lc[NB];
    int tid = threadIdx.x;
    int cs = blockIdx.x * CHUNK;
    int cn = min(CHUNK, nedges - cs);
    for (int i = tid; i < NB; i += 512) { lh[i] = 0; lc[i] = 0; }
    __syncthreads();
    for (int i = tid; i < cn; i += 512)
        atomicAdd(&lh[rows[cs + i] >> SH], 1);
    __syncthreads();
    for (int b = tid; b < NB; b += 512) {
        int h = lh[b];
        if (h) gb[b] = atomicAdd(&cursor[b], h);
    }
    __syncthreads();
    for (int i = tid; i < cn; i += 512) {
        int e = cs + i;
        int r = rows[e];
        int b = r >> SH;
        int p = atomicAdd(&lc[b], 1);
        rec[gb[b] + p] = make_int2(((r & (RPB - 1)) << 18) | cols[e],
                                   __float_as_int(vals[e]));
    }
}

// ---- per-bucket LDS counting sort: rec (bucket-grouped) -> rec (row-sorted,
//      repacked as (col,val)), and emit full CSR row_start ----
__global__ __launch_bounds__(512)
void sort_bucket(int2* __restrict__ rec, const int* __restrict__ base,
                 int* __restrict__ row_start) {
    __shared__ int2 lrec[CAP];                 // 64 KB
    __shared__ int cnt[RPB], cur[RPB];
    __shared__ int wtot;
    const int b = blockIdx.x, tid = threadIdx.x;
    const int s = base[b], e = base[b + 1], n = e - s;
    for (int i = tid; i < RPB; i += 512) cnt[i] = 0;
    __syncthreads();
    for (int i = tid; i < n; i += 512) {
        int2 r = rec[s + i];                   // coalesced
        lrec[i] = r;
        atomicAdd(&cnt[((unsigned)r.x) >> 18], 1);
    }
    __syncthreads();
    // exclusive scan of cnt[0..127] using waves 0,1
    int lane = tid & 63;
    int v = (tid < 128) ? cnt[tid] : 0;
    int sc = v;
    #pragma unroll
    for (int d = 1; d < 64; d <<= 1) { int t = __shfl_up(sc, d); if (lane >= d) sc += t; }
    if (tid == 63) wtot = sc;
    __syncthreads();
    if (tid < 128) {
        int ex = sc - v + ((tid >= 64) ? wtot : 0);
        cur[tid] = ex;
        int idx = b * RPB + tid;
        if (idx <= N_NODES) row_start[idx] = s + ex;
    }
    __syncthreads();
    for (int i = tid; i < n; i += 512) {
        int2 r = lrec[i];
        unsigned rx = (unsigned)r.x;
        int pos = atomicAdd(&cur[rx >> 18], 1);
        rec[s + pos] = make_int2((int)(rx & 0x3FFFF), r.y);   // (col, val)
    }
}

// ---- convert f32 (ue|ie) -> contiguous bf16 ego table ----
__global__ __launch_bounds__(256)
void cvt_ego(const float* __restrict__ ue, const float* __restrict__ ie,
             unsigned short* __restrict__ ego) {
    const int total4 = N_NODES * EMB / 4;
    const int userEnd4 = N_USERS * EMB / 4;
    int stride = gridDim.x * blockDim.x;
    for (int i = blockIdx.x * blockDim.x + threadIdx.x; i < total4; i += stride) {
        float4 v = (i < userEnd4) ? ((const float4*)ue)[i]
                                  : ((const float4*)ie)[i - userEnd4];
        ushort4 o;
        o.x = f2bf(v.x); o.y = f2bf(v.y); o.z = f2bf(v.z); o.w = f2bf(v.w);
        ((ushort4*)ego)[i] = o;
    }
}

// ---- SpMM: one wave per row, register accumulate.
//      Zero-padded 16-wide unconditional gather batches (16 misses in flight). ----
__global__ __launch_bounds__(256)
void spmm_row(const int2* __restrict__ rec, const int* __restrict__ row_start,
              const unsigned short* __restrict__ x, unsigned short* __restrict__ y) {
    const int lane = threadIdx.x & 63;
    const int wave = (blockIdx.x * blockDim.x + threadIdx.x) >> 6;
    const int nw = (gridDim.x * blockDim.x) >> 6;
    for (int r = wave; r < N_NODES; r += nw) {
        const int s = row_start[r], e = row_start[r + 1];
        float acc = 0.f;
        for (int k0 = s; k0 < e; k0 += 64) {
            int kk = k0 + lane;
            int2 rc = make_int2(0, 0);            // zero-pad: v=0 -> fma no-op
            if (kk < e) rc = rec[kk];             // coalesced: 64 edges per wave
            int cnt = min(64, e - k0);
            for (int j = 0; j < cnt; j += 16) {
#define EDGE_LD(t) \
                int   c##t = __shfl(rc.x, j + t); \
                float v##t = __int_as_float(__shfl(rc.y, j + t)); \
                float x##t = bf2f(x[((size_t)c##t << 6) | lane]);
                EDGE_LD(0)  EDGE_LD(1)  EDGE_LD(2)  EDGE_LD(3)
                EDGE_LD(4)  EDGE_LD(5)  EDGE_LD(6)  EDGE_LD(7)
                EDGE_LD(8)  EDGE_LD(9)  EDGE_LD(10) EDGE_LD(11)
                EDGE_LD(12) EDGE_LD(13) EDGE_LD(14) EDGE_LD(15)
#undef EDGE_LD
                acc = fmaf(v0,  x0,  acc);
                acc = fmaf(v1,  x1,  acc);
                acc = fmaf(v2,  x2,  acc);
                acc = fmaf(v3,  x3,  acc);
                acc = fmaf(v4,  x4,  acc);
                acc = fmaf(v5,  x5,  acc);
                acc = fmaf(v6,  x6,  acc);
                acc = fmaf(v7,  x7,  acc);
                acc = fmaf(v8,  x8,  acc);
                acc = fmaf(v9,  x9,  acc);
                acc = fmaf(v10, x10, acc);
                acc = fmaf(v11, x11, acc);
                acc = fmaf(v12, x12, acc);
                acc = fmaf(v13, x13, acc);
                acc = fmaf(v14, x14, acc);
                acc = fmaf(v15, x15, acc);
            }
        }
        y[(size_t)r * EMB + lane] = f2bf(acc);
    }
}

// ---- batch-row output kernels ----
// out = ego_sel (f32 exact) + h1_sel
__global__ void out_first(const int* __restrict__ user, const int* __restrict__ item,
                          const float* __restrict__ ue, const float* __restrict__ ie,
                          const unsigned short* __restrict__ h1,
                          float* __restrict__ out, int batch) {
    int wave = (blockIdx.x * blockDim.x + threadIdx.x) >> 6;
    int lane = threadIdx.x & 63;
    if (wave >= 2 * batch) return;
    float egov;
    int node;
    if (wave < batch) {
        int u = user[wave];
        node = u;
        egov = ue[(size_t)u * EMB + lane];
    } else {
        int it = item[wave - batch];
        node = N_USERS + it;
        egov = ie[(size_t)it * EMB + lane];
    }
    out[(size_t)wave * EMB + lane] = egov + bf2f(h1[(size_t)node * EMB + lane]);
}

__global__ void out_add(const int* __restrict__ user, const int* __restrict__ item,
                        const unsigned short* __restrict__ h, float* __restrict__ out,
                        int batch, float scale) {
    int wave = (blockIdx.x * blockDim.x + threadIdx.x) >> 6;
    int lane = threadIdx.x & 63;
    if (wave < 2 * batch) {
        int node = (wave < batch) ? user[wave] : (N_USERS + item[wave - batch]);
        size_t o = (size_t)wave * EMB + lane;
        out[o] = (out[o] + bf2f(h[(size_t)node * EMB + lane])) * scale;
    }
}

// ---- driver ----
extern "C" void kernel_launch(void* const* d_in, const int* in_sizes, int n_in,
                              void* d_out, int out_size, void* d_ws, size_t ws_size,
                              hipStream_t stream) {
    const int*   user = (const int*)d_in[0];
    const int*   item = (const int*)d_in[1];
    const int*   rows = (const int*)d_in[2];
    const int*   cols = (const int*)d_in[3];
    const float* vals = (const float*)d_in[4];
    const float* ue   = (const float*)d_in[5];
    const float* ie   = (const float*)d_in[6];
    float*       out  = (float*)d_out;

    const int nedges = in_sizes[2];
    const int batch  = in_sizes[0];

    const size_t hElems = (size_t)N_NODES * EMB;
    char* p = (char*)d_ws;
    int2*           rec       = (int2*)p;            p += (size_t)nedges * sizeof(int2); // 51.2 MB
    int*            bh        = (int*)p;             p += 8192;
    int*            base      = (int*)p;             p += 8192;   // NB+1 ints
    int*            cursor    = (int*)p;             p += 8192;
    int*            row_start = (int*)p;             p += 600064; // N_NODES+1 ints, padded
    unsigned short* ego       = (unsigned short*)p;  p += hElems * 2;   // 19.2 MB
    unsigned short* hA        = (unsigned short*)p;  p += hElems * 2;
    unsigned short* hB        = (unsigned short*)p;  p += hElems * 2;

    // --- CSR build: coarse bucket sort, then per-bucket LDS counting sort ---
    hipMemsetAsync(bh, 0, NB * sizeof(int), stream);
    bucket_hist<<<1024, 256, 0, stream>>>(rows, bh, nedges);
    scan_single<<<1, 1024, 0, stream>>>(bh, base, cursor, nedges);
    bucket_scatter<<<(nedges + CHUNK - 1) / CHUNK, 512, 0, stream>>>(
        rows, cols, vals, cursor, rec, nedges);
    sort_bucket<<<NB, 512, 0, stream>>>(rec, base, row_start);

    // --- ego table in bf16 ---
    cvt_ego<<<2048, 256, 0, stream>>>(ue, ie, ego);

    // --- 3 propagation layers (wave-per-row, register acc) ---
    const int oblocks = (2 * batch * 64) / 256;

    spmm_row<<<2048, 256, 0, stream>>>(rec, row_start, ego, hA);
    out_first<<<oblocks, 256, 0, stream>>>(user, item, ue, ie, hA, out, batch);

    spmm_row<<<2048, 256, 0, stream>>>(rec, row_start, hA, hB);
    out_add<<<oblocks, 256, 0, stream>>>(user, item, hB, out, batch, 1.0f);

    spmm_row<<<2048, 256, 0, stream>>>(rec, row_start, hB, hA);
    out_add<<<oblocks, 256, 0, stream>>>(user, item, hA, out, batch, 0.25f);
}